// Round 15
// baseline (384.984 us; speedup 1.0000x reference)
//
#include <hip/hip_runtime.h>
#include <stdint.h>

constexpr int INSZ = 224;
constexpr int GD   = 53;
constexpr int C0R = 8427, C1R = 2106, C2R = 526;
constexpr int C0P = 8448, C1P = 2304, C2P = 640;   // padded strides
constexpr int NTOK = 2048;
constexpr int CROW = GD * 16;  // 848
constexpr int K1EFF = 2112;    // GEMM4 main: 66 kt

typedef __attribute__((ext_vector_type(4))) float f32x4;
typedef __attribute__((ext_vector_type(8))) short bf16x8;

constexpr float CT[64] = {
  1.00000000f,  0.99518473f,  0.98078528f,  0.95694034f,
  0.92387953f,  0.88192126f,  0.83146961f,  0.77301045f,
  0.70710678f,  0.63439328f,  0.55557023f,  0.47139674f,
  0.38268343f,  0.29028468f,  0.19509032f,  0.09801714f,
  0.00000000f, -0.09801714f, -0.19509032f, -0.29028468f,
 -0.38268343f, -0.47139674f, -0.55557023f, -0.63439328f,
 -0.70710678f, -0.77301045f, -0.83146961f, -0.88192126f,
 -0.92387953f, -0.95694034f, -0.98078528f, -0.99518473f,
 -1.00000000f, -0.99518473f, -0.98078528f, -0.95694034f,
 -0.92387953f, -0.88192126f, -0.83146961f, -0.77301045f,
 -0.70710678f, -0.63439328f, -0.55557023f, -0.47139674f,
 -0.38268343f, -0.29028468f, -0.19509032f, -0.09801714f,
 -0.00000000f,  0.09801714f,  0.19509032f,  0.29028468f,
  0.38268343f,  0.47139674f,  0.55557023f,  0.63439328f,
  0.70710678f,  0.77301045f,  0.83146961f,  0.88192126f,
  0.92387953f,  0.95694034f,  0.98078528f,  0.99518473f
};
constexpr float Dfwd(int k, int n) { return 2.0f * CT[((2 * n + 1) * k) & 63]; }
constexpr float Dinv(int n, int k) { return CT[((2 * n + 1) * k) & 63] * (k == 0 ? 0.03125f : 0.0625f); }

constexpr int TRS_R = 20, TRS_T = 336;
constexpr int TRS_SZ = 15 * TRS_T + 15 * TRS_R + 16;
constexpr int HST_S = 68;   // hst row stride (ushorts): 136B breaks the 128B bank period

__device__ __forceinline__ unsigned short f2bf(float f) {
  union { float f; unsigned u; } v; v.f = f;
  return (unsigned short)((v.u + 0x7FFFu + ((v.u >> 16) & 1u)) >> 16);
}
__device__ __forceinline__ float bf2f(unsigned short b) {
  union { unsigned u; float f; } v; v.u = ((unsigned)b) << 16;
  return v.f;
}

__device__ __forceinline__ void gload_lds16(const void* g, void* l) {
  __builtin_amdgcn_global_load_lds(
      (__attribute__((address_space(1))) unsigned int*)(uintptr_t)g,
      (__attribute__((address_space(3))) unsigned int*)(unsigned int)(uintptr_t)l,
      16, 0, 0);
}

// XCD swizzle + L2 supertiling (4-wide bx stripes, by inner). requires (gx*gy)%8==0
__device__ __forceinline__ void xcd_tile(int& bx, int& by) {
  const int gx = gridDim.x, gy = gridDim.y;
  const int nwg = gx * gy;
  const int bid = blockIdx.y * gx + blockIdx.x;
  const int cpx = nwg >> 3;
  const int l = (bid & 7) * cpx + (bid >> 3);
  const int stripe = gy << 2;
  const int bxg = l / stripe;
  const int r = l - bxg * stripe;
  const int rem = gx - (bxg << 2);
  const int w = rem < 4 ? rem : 4;
  by = r / w;
  bx = (bxg << 2) + (r - by * w);
}

// -------- w1 fp32 -> bf16 padded, 8 elems/thread, uint4 store (no LDS) --------
constexpr int CV1_GPR = C0P / 8;
constexpr int CV1_TOT = C1P * CV1_GPR;
__global__ __launch_bounds__(256)
void cvt_pad8_w1(const float* __restrict__ src, unsigned short* __restrict__ dst) {
  const int i = blockIdx.x * 256 + threadIdx.x;
  if (i >= CV1_TOT) return;
  const int m = i / CV1_GPR;
  const int k0 = (i - m * CV1_GPR) * 8;
  const float* sr = src + (size_t)m * C0R + k0;
  const bool mok = (m < C1R);
  unsigned short h[8];
#pragma unroll
  for (int e = 0; e < 8; ++e)
    h[e] = f2bf((mok && k0 + e < C0R) ? sr[e] : 0.f);
  uint4 pk;
  pk.x = (unsigned)h[0] | ((unsigned)h[1] << 16);
  pk.y = (unsigned)h[2] | ((unsigned)h[3] << 16);
  pk.z = (unsigned)h[4] | ((unsigned)h[5] << 16);
  pk.w = (unsigned)h[6] | ((unsigned)h[7] << 16);
  *(uint4*)&dst[(size_t)m * C0P + k0] = pk;
}

// -------- DCT: x -> H0 bf16 [n=2048][c=8448]; hst stride 68 kills bank conflicts --------
__global__ __launch_bounds__(256)
void dct_h0(const float* __restrict__ x, unsigned short* __restrict__ H0) {
  __shared__ float trp[TRS_SZ];
  __shared__ unsigned short hst[256 * HST_S];
  const int tid = threadIdx.x;
  const int b   = blockIdx.y;
  const int c0  = blockIdx.x * 64;
  const int t = tid >> 4, q = tid & 15;

  for (int g = 0; g < 4; ++g) {
    const int c = c0 + g * 16 + t;
    float p[16];
    {
      float4 v0{}, v1{}, v2{}, v3{};
      if (c < C0R) {
        const int ch = c % 3, gw = (c / 3) % GD, gh = c / (3 * GD);
        const float* xr = x + ((size_t)(b * 3 + ch) * INSZ + (gh * 4 + q)) * INSZ + gw * 4;
        v0 = *(const float4*)(xr);      v1 = *(const float4*)(xr + 4);
        v2 = *(const float4*)(xr + 8);  v3 = *(const float4*)(xr + 12);
      }
      p[0]=v0.x; p[1]=v0.y; p[2]=v0.z; p[3]=v0.w;
      p[4]=v1.x; p[5]=v1.y; p[6]=v1.z; p[7]=v1.w;
      p[8]=v2.x; p[9]=v2.y; p[10]=v2.z; p[11]=v2.w;
      p[12]=v3.x; p[13]=v3.y; p[14]=v3.z; p[15]=v3.w;
    }
    float r[16];
#pragma unroll
    for (int k = 0; k < 16; ++k) {
      float s = 0.f;
#pragma unroll
      for (int n = 0; n < 16; ++n) s += p[n] * Dfwd(k, n);
      r[k] = s;
    }
    float* wr = &trp[t * TRS_T + q * TRS_R];
#pragma unroll
    for (int k = 0; k < 16; k += 4)
      *(float4*)(wr + k) = make_float4(r[k], r[k+1], r[k+2], r[k+3]);
    __syncthreads();
    const int j = q;
    float rr[16];
#pragma unroll
    for (int i = 0; i < 16; ++i) rr[i] = trp[t * TRS_T + i * TRS_R + j];
#pragma unroll
    for (int k = 0; k < 16; ++k) {
      float s = 0.f;
#pragma unroll
      for (int i = 0; i < 16; ++i) s += rr[i] * Dfwd(k, i);
      hst[(k * 16 + j) * HST_S + g * 16 + t] = f2bf(s * (1.f / 256.f));
    }
    __syncthreads();
  }
  const size_t base = ((size_t)b * 256) * C0P + c0;
#pragma unroll
  for (int i = 0; i < 8; ++i) {
    const int s = i * 256 + tid;
    const int kl = s >> 3, c16 = s & 7;
    *(uint4*)&H0[base + (size_t)kl * C0P + c16 * 8] = *(const uint4*)&hst[kl * HST_S + c16 * 8];
  }
}

// ======== fused stage 2: reduce_act(GEMM1) || cvt_pad8_all (no LDS) ========
constexpr int M1_RB = NTOK * C1P / 8 / 256;
constexpr int CV8_1 = C2P * C1P / 8;
constexpr int CV8_2 = CV8_1 + C1P * C2P / 8;
constexpr int CV8_T = CV8_2 + C0P * C1P / 8;
__global__ __launch_bounds__(256)
void mid1(const float* __restrict__ part, const float* __restrict__ b1,
          unsigned short* __restrict__ Y1,
          const float* __restrict__ w2, const float* __restrict__ w3,
          const float* __restrict__ w4, unsigned short* __restrict__ d2,
          unsigned short* __restrict__ d3, unsigned short* __restrict__ d4) {
  const int tid = threadIdx.x;
  if ((int)blockIdx.x < M1_RB) {
    const int i8 = blockIdx.x * 256 + tid;
    const size_t off = (size_t)i8 * 8;
    const int m0 = (int)(off % C1P);
    float s[8] = {0.f, 0.f, 0.f, 0.f, 0.f, 0.f, 0.f, 0.f};
    for (int z = 0; z < 3; ++z) {
      const float4 v0 = *(const float4*)(part + (size_t)z * NTOK * C1P + off);
      const float4 v1 = *(const float4*)(part + (size_t)z * NTOK * C1P + off + 4);
      s[0] += v0.x; s[1] += v0.y; s[2] += v0.z; s[3] += v0.w;
      s[4] += v1.x; s[5] += v1.y; s[6] += v1.z; s[7] += v1.w;
    }
    unsigned short h[8];
#pragma unroll
    for (int e = 0; e < 8; ++e) {
      const float b = (m0 + e < C1R) ? b1[m0 + e] : 0.f;
      h[e] = f2bf(fmaxf(s[e] + b, 0.f));
    }
    uint4 pk;
    pk.x = (unsigned)h[0] | ((unsigned)h[1] << 16);
    pk.y = (unsigned)h[2] | ((unsigned)h[3] << 16);
    pk.z = (unsigned)h[4] | ((unsigned)h[5] << 16);
    pk.w = (unsigned)h[6] | ((unsigned)h[7] << 16);
    *(uint4*)&Y1[off] = pk;
    return;
  }
  const int i = (blockIdx.x - M1_RB) * 256 + tid;
  const float* src; unsigned short* dst;
  int m, k0, Kreal, Mreal, Kp;
  if (i < CV8_1) {
    const int gpr = C1P / 8;
    m = i / gpr; k0 = (i - m * gpr) * 8;
    src = w2; dst = d2; Mreal = C2R; Kreal = C1R; Kp = C1P;
  } else if (i < CV8_2) {
    const int j = i - CV8_1;
    const int gpr = C2P / 8;
    m = j / gpr; k0 = (j - m * gpr) * 8;
    src = w3; dst = d3; Mreal = C1R; Kreal = C2R; Kp = C2P;
  } else {
    const int j = i - CV8_2;
    const int gpr = C1P / 8;
    m = j / gpr; k0 = (j - m * gpr) * 8;
    src = w4; dst = d4; Mreal = C0R; Kreal = C1R; Kp = C1P;
  }
  const float* sr = src + (size_t)m * Kreal + k0;
  const bool mok = (m < Mreal);
  unsigned short h[8];
#pragma unroll
  for (int e = 0; e < 8; ++e)
    h[e] = f2bf((mok && k0 + e < Kreal) ? sr[e] : 0.f);
  uint4 pk;
  pk.x = (unsigned)h[0] | ((unsigned)h[1] << 16);
  pk.y = (unsigned)h[2] | ((unsigned)h[3] << 16);
  pk.z = (unsigned)h[4] | ((unsigned)h[5] << 16);
  pk.w = (unsigned)h[6] | ((unsigned)h[7] << 16);
  *(uint4*)&dst[(size_t)m * Kp + k0] = pk;
}

// ======== 256x256 deep-pipelined GEMM (frozen schedule).
// ======== grid = (8 [by, locks one N-panel per XCD], M-tiles [, z]).
// ======== B-panel (~1.1-1.4 MB) stays L2-resident per XCD; W streams via L3.
template<int ACT, int OUT_NM, int SPLITK>
__global__ __launch_bounds__(512, 2)
void gemm256(const unsigned short* __restrict__ W, const unsigned short* __restrict__ Ht,
             const float* __restrict__ bias, void* __restrict__ outp,
             int ldo, int Kp, int chunkK) {
  __shared__ unsigned short As[4][8192];
  __shared__ unsigned short Bs[4][8192];
  const int by = blockIdx.x;   // gridDim.x == 8: XCD id == by (linear id mod 8)
  const int bx = blockIdx.y;
  const int m0 = bx * 256, n0 = by * 256;
  const int tid = threadIdx.x;
  const int w = tid >> 6, lane = tid & 63;
  const int wr = w >> 2, wc = w & 3;
  const int lhi = lane >> 4, llo = lane & 15;
  const int kbase = SPLITK ? blockIdx.z * chunkK : 0;
  const int nkt = chunkK >> 5;

  const int srow = tid >> 2;
  const int slgc = ((tid & 3) ^ ((srow >> 1) & 3)) * 8;

  f32x4 acc[8][4];
#pragma unroll
  for (int i = 0; i < 8; ++i)
#pragma unroll
    for (int j = 0; j < 4; ++j) acc[i][j] = f32x4{0.f, 0.f, 0.f, 0.f};

  auto STAGE_A = [&](int kt, int buf) {
    const int kb = kbase + kt * 32 + slgc;
    gload_lds16(W + (size_t)(m0 + srow) * Kp + kb,       &As[buf][w * 512]);
    gload_lds16(W + (size_t)(m0 + 128 + srow) * Kp + kb, &As[buf][4096 + w * 512]);
  };
  auto STAGE_B = [&](int kt, int buf) {
    const int kb = kbase + kt * 32 + slgc;
    gload_lds16(Ht + (size_t)(n0 + srow) * Kp + kb,       &Bs[buf][w * 512]);
    gload_lds16(Ht + (size_t)(n0 + 128 + srow) * Kp + kb, &Bs[buf][4096 + w * 512]);
  };

  STAGE_A(0, 0); STAGE_B(0, 0);
  if (nkt > 1) { STAGE_A(1, 1); STAGE_B(1, 1); }
  if (nkt > 2) { STAGE_A(2, 2); STAGE_B(2, 2); }

  for (int kt = 0; kt < nkt; ++kt) {
    const int buf  = kt & 3;
    const int sbuf = (kt + 3) & 3;
    if (kt + 3 <= nkt)      asm volatile("s_waitcnt vmcnt(8)" ::: "memory");
    else if (kt + 2 == nkt) asm volatile("s_waitcnt vmcnt(4)" ::: "memory");
    else                    asm volatile("s_waitcnt vmcnt(0)" ::: "memory");
    __builtin_amdgcn_s_barrier();
    __builtin_amdgcn_sched_barrier(0);

    bf16x8 af[4], bfr[4];
    // phase A: m-half 0 + all B frags
#pragma unroll
    for (int mi = 0; mi < 4; ++mi) {
      const int row = wr * 128 + mi * 16 + llo;
      af[mi] = *(const bf16x8*)(&As[buf][row * 32 + ((lhi ^ ((row >> 1) & 3)) << 3)]);
    }
#pragma unroll
    for (int ni = 0; ni < 4; ++ni) {
      const int row = wc * 64 + ni * 16 + llo;
      bfr[ni] = *(const bf16x8*)(&Bs[buf][row * 32 + ((lhi ^ ((row >> 1) & 3)) << 3)]);
    }
    if (kt + 3 < nkt) STAGE_A(kt + 3, sbuf);
    __builtin_amdgcn_s_setprio(1);
#pragma unroll
    for (int mi = 0; mi < 4; ++mi)
#pragma unroll
      for (int ni = 0; ni < 4; ++ni)
        acc[mi][ni] = OUT_NM
          ? __builtin_amdgcn_mfma_f32_16x16x32_bf16(bfr[ni], af[mi], acc[mi][ni], 0, 0, 0)
          : __builtin_amdgcn_mfma_f32_16x16x32_bf16(af[mi], bfr[ni], acc[mi][ni], 0, 0, 0);
    __builtin_amdgcn_s_setprio(0);
    // phase B: m-half 1, reuse bfr
#pragma unroll
    for (int mi = 0; mi < 4; ++mi) {
      const int row = wr * 128 + 64 + mi * 16 + llo;
      af[mi] = *(const bf16x8*)(&As[buf][row * 32 + ((lhi ^ ((row >> 1) & 3)) << 3)]);
    }
    if (kt + 3 < nkt) STAGE_B(kt + 3, sbuf);
    __builtin_amdgcn_s_setprio(1);
#pragma unroll
    for (int mi = 0; mi < 4; ++mi)
#pragma unroll
      for (int ni = 0; ni < 4; ++ni)
        acc[4 + mi][ni] = OUT_NM
          ? __builtin_amdgcn_mfma_f32_16x16x32_bf16(bfr[ni], af[mi], acc[4 + mi][ni], 0, 0, 0)
          : __builtin_amdgcn_mfma_f32_16x16x32_bf16(af[mi], bfr[ni], acc[4 + mi][ni], 0, 0, 0);
    __builtin_amdgcn_s_setprio(0);
  }

  if (SPLITK) {
    float* pz = (float*)outp + (size_t)blockIdx.z * ((size_t)NTOK * ldo);
#pragma unroll
    for (int mh = 0; mh < 2; ++mh)
#pragma unroll
      for (int mi = 0; mi < 4; ++mi) {
        const int mg = m0 + wr * 128 + mh * 64 + mi * 16 + llo;
#pragma unroll
        for (int ni = 0; ni < 4; ++ni) {
          const int ng = n0 + wc * 64 + ni * 16 + lhi * 4;
#pragma unroll
          for (int r = 0; r < 4; ++r)
            pz[(size_t)(ng + r) * ldo + mg] = acc[mh * 4 + mi][ni][r];
        }
      }
  } else {
    unsigned short* out = (unsigned short*)outp;
#pragma unroll
    for (int mh = 0; mh < 2; ++mh)
#pragma unroll
      for (int mi = 0; mi < 4; ++mi) {
        const int mgb = m0 + wr * 128 + mh * 64 + mi * 16 + lhi * 4;
#pragma unroll
        for (int ni = 0; ni < 4; ++ni) {
          const int ng = n0 + wc * 64 + ni * 16 + llo;
#pragma unroll
          for (int r = 0; r < 4; ++r) {
            const int mg = mgb + r;
            float v = acc[mh * 4 + mi][ni][r] + bias[mg];
            if (ACT == 1) v = fmaxf(v, 0.f);
            else if (ACT == 2) v = 1.f / (1.f + expf(-v));
            out[(size_t)mg * ldo + ng] = f2bf(v);
          }
        }
      }
  }
}

// ======== 128x128 core (GEMM2/3 + GEMM4 tail splitk) ========
template<int OUT_NM>
__device__ __forceinline__ void gemm_core(
    const unsigned short* __restrict__ W, const unsigned short* __restrict__ Ht,
    unsigned short (*As)[128 * 32], unsigned short (*Bs)[128 * 32],
    int m0, int n0, int Kp, int kbase, int nkt, int w, int lane, f32x4 acc[4][4]) {
  const int wr = w >> 1, wc = w & 1;
  const int lhi = lane >> 4, llo = lane & 15;

  const int chunk0 = w * 64 + lane;
  const int row0 = chunk0 >> 2, kc0 = chunk0 & 3;
  const int kcg0 = kc0 ^ ((row0 >> 1) & 3);
  const int chunk1 = 256 + w * 64 + lane;
  const int row1 = chunk1 >> 2, kc1 = chunk1 & 3;
  const int kcg1 = kc1 ^ ((row1 >> 1) & 3);

  auto STAGE = [&](int kt, int sel) {
    const int kb = kbase + kt * 32;
    gload_lds16(W  + (size_t)(m0 + row0) * Kp + kb + kcg0 * 8, &As[sel][(w * 64) * 8]);
    gload_lds16(Ht + (size_t)(n0 + row0) * Kp + kb + kcg0 * 8, &Bs[sel][(w * 64) * 8]);
    gload_lds16(W  + (size_t)(m0 + row1) * Kp + kb + kcg1 * 8, &As[sel][(256 + w * 64) * 8]);
    gload_lds16(Ht + (size_t)(n0 + row1) * Kp + kb + kcg1 * 8, &Bs[sel][(256 + w * 64) * 8]);
  };

  STAGE(0, 0);
  if (nkt > 1) STAGE(1, 1);

  int cur = 0, nxt = 1, nx2 = 2;
  for (int kt = 0; kt < nkt; ++kt) {
    if (kt + 1 < nkt) {
      asm volatile("s_waitcnt vmcnt(4)" ::: "memory");
      __builtin_amdgcn_s_barrier();
      __builtin_amdgcn_sched_barrier(0);
      if (kt + 2 < nkt) STAGE(kt + 2, nx2);
    } else {
      asm volatile("s_waitcnt vmcnt(0)" ::: "memory");
      __builtin_amdgcn_s_barrier();
      __builtin_amdgcn_sched_barrier(0);
    }
    bf16x8 af[4], bfr[4];
#pragma unroll
    for (int mi = 0; mi < 4; ++mi) {
      const int row = wr * 64 + mi * 16 + llo;
      af[mi] = *(const bf16x8*)(&As[cur][row * 32 + (lhi ^ ((row >> 1) & 3)) * 8]);
    }
#pragma unroll
    for (int ni = 0; ni < 4; ++ni) {
      const int row = wc * 64 + ni * 16 + llo;
      bfr[ni] = *(const bf16x8*)(&Bs[cur][row * 32 + (lhi ^ ((row >> 1) & 3)) * 8]);
    }
#pragma unroll
    for (int mi = 0; mi < 4; ++mi)
#pragma unroll
      for (int ni = 0; ni < 4; ++ni) {
        if (OUT_NM)
          acc[mi][ni] = __builtin_amdgcn_mfma_f32_16x16x32_bf16(bfr[ni], af[mi], acc[mi][ni], 0, 0, 0);
        else
          acc[mi][ni] = __builtin_amdgcn_mfma_f32_16x16x32_bf16(af[mi], bfr[ni], acc[mi][ni], 0, 0, 0);
      }
    const int tmp = cur; cur = nxt; nxt = nx2; nx2 = tmp;
  }
}

// -------- 128^2 split-K, n-major partials [z][n][m] (GEMM2/3) --------
__global__ __launch_bounds__(256)
void gemm_splitk(const unsigned short* __restrict__ W, const unsigned short* __restrict__ Ht,
                 float* __restrict__ part, int ldo /*Mp*/, int Kp, int chunkK) {
  __shared__ unsigned short As[3][128 * 32];
  __shared__ unsigned short Bs[3][128 * 32];
  int bx, by; xcd_tile(bx, by);
  const int z = blockIdx.z;
  const int tid = threadIdx.x;
  const int w = tid >> 6, lane = tid & 63;
  const int m0 = bx * 128, n0 = by * 128;
  const int wr = w >> 1, wc = w & 1;
  const int lhi = lane >> 4, llo = lane & 15;

  f32x4 acc[4][4];
#pragma unroll
  for (int i = 0; i < 4; ++i)
#pragma unroll
    for (int j = 0; j < 4; ++j) acc[i][j] = f32x4{0.f, 0.f, 0.f, 0.f};

  gemm_core<1>(W, Ht, As, Bs, m0, n0, Kp, z * chunkK, chunkK >> 5, w, lane, acc);

  float* pz = part + (size_t)z * NTOK * ldo;
#pragma unroll
  for (int mi = 0; mi < 4; ++mi) {
    const int mg = m0 + wr * 64 + mi * 16 + llo;
#pragma unroll
    for (int ni = 0; ni < 4; ++ni) {
      const int ng = n0 + wc * 64 + ni * 16 + lhi * 4;
#pragma unroll
      for (int r = 0; r < 4; ++r)
        pz[(size_t)(ng + r) * ldo + mg] = acc[mi][ni][r];
    }
  }
}

// -------- 128^2 split-K, m-major partials [z][m_local][n] (GEMM4 tail) --------
__global__ __launch_bounds__(256)
void gemm_splitk_mn(const unsigned short* __restrict__ W, const unsigned short* __restrict__ Ht,
                    float* __restrict__ part, int Kp, int chunkK) {
  __shared__ unsigned short As[3][128 * 32];
  __shared__ unsigned short Bs[3][128 * 32];
  int bx, by; xcd_tile(bx, by);
  const int z = blockIdx.z;
  const int tid = threadIdx.x;
  const int w = tid >> 6, lane = tid & 63;
  const int m0 = bx * 128, n0 = by * 128;
  const int wr = w >> 1, wc = w & 1;
  const int lhi = lane >> 4, llo = lane & 15;
  const int Mloc = gridDim.x * 128;

  f32x4 acc[4][4];
#pragma unroll
  for (int i = 0; i < 4; ++i)
#pragma unroll
    for (int j = 0; j < 4; ++j) acc[i][j] = f32x4{0.f, 0.f, 0.f, 0.f};

  gemm_core<0>(W, Ht, As, Bs, m0, n0, Kp, z * chunkK, chunkK >> 5, w, lane, acc);

  float* pz = part + (size_t)z * Mloc * NTOK;
#pragma unroll
  for (int mi = 0; mi < 4; ++mi) {
    const int mlb = m0 + wr * 64 + mi * 16 + lhi * 4;
#pragma unroll
    for (int ni = 0; ni < 4; ++ni) {
      const int ng = n0 + wc * 64 + ni * 16 + llo;
#pragma unroll
      for (int r = 0; r < 4; ++r)
        pz[(size_t)(mlb + r) * NTOK + ng] = acc[mi][ni][r];
    }
  }
}

// -------- tail reduce + bias + sigmoid --------
__global__ __launch_bounds__(256)
void reduce_sig(const float* __restrict__ part, const float* __restrict__ bias,
                unsigned short* __restrict__ msk, int mbase, int Mloc, int nch) {
  const int i8 = blockIdx.x * 256 + threadIdx.x;
  const int total = Mloc * NTOK / 8;
  if (i8 >= total) return;
  const size_t off = (size_t)i8 * 8;
  const int ml = (int)(off >> 11);
  float s[8] = {0.f, 0.f, 0.f, 0.f, 0.f, 0.f, 0.f, 0.f};
  for (int z = 0; z < nch; ++z) {
    const float4 v0 = *(const float4*)(part + (size_t)z * Mloc * NTOK + off);
    const float4 v1 = *(const float4*)(part + (size_t)z * Mloc * NTOK + off + 4);
    s[0] += v0.x; s[1] += v0.y; s[2] += v0.z; s[3] += v0.w;
    s[4] += v1.x; s[5] += v1.y; s[6] += v1.z; s[7] += v1.w;
  }
  const int mg = mbase + ml;
  const float b = (mg < C0R) ? bias[mg] : 0.f;
  unsigned short h[8];
#pragma unroll
  for (int e = 0; e < 8; ++e)
    h[e] = f2bf(1.f / (1.f + expf(-(s[e] + b))));
  uint4 pk;
  pk.x = (unsigned)h[0] | ((unsigned)h[1] << 16);
  pk.y = (unsigned)h[2] | ((unsigned)h[3] << 16);
  pk.z = (unsigned)h[4] | ((unsigned)h[5] << 16);
  pk.w = (unsigned)h[6] | ((unsigned)h[7] << 16);
  *(uint4*)&msk[(size_t)mg * NTOK + (off & 2047)] = pk;
}

// -------- split-K reduce + bias + ReLU (GEMM2/3) --------
__global__ __launch_bounds__(256)
void reduce_act(const float* __restrict__ part, const float* __restrict__ bias,
                unsigned short* __restrict__ out, int Mp, int Mreal, int nch) {
  const int i8 = blockIdx.x * 256 + threadIdx.x;
  const int total = NTOK * Mp / 8;
  if (i8 >= total) return;
  const size_t off = (size_t)i8 * 8;
  const int m0 = (int)(off % Mp);
  float s[8] = {0.f, 0.f, 0.f, 0.f, 0.f, 0.f, 0.f, 0.f};
  for (int z = 0; z < nch; ++z) {
    const float4 v0 = *(const float4*)(part + (size_t)z * NTOK * Mp + off);
    const float4 v1 = *(const float4*)(part + (size_t)z * NTOK * Mp + off + 4);
    s[0] += v0.x; s[1] += v0.y; s[2] += v0.z; s[3] += v0.w;
    s[4] += v1.x; s[5] += v1.y; s[6] += v1.z; s[7] += v1.w;
  }
  unsigned short h[8];
#pragma unroll
  for (int e = 0; e < 8; ++e) {
    const float b = (m0 + e < Mreal) ? bias[m0 + e] : 0.f;
    h[e] = f2bf(fmaxf(s[e] + b, 0.f));
  }
  uint4 pk;
  pk.x = (unsigned)h[0] | ((unsigned)h[1] << 16);
  pk.y = (unsigned)h[2] | ((unsigned)h[3] << 16);
  pk.z = (unsigned)h[4] | ((unsigned)h[5] << 16);
  pk.w = (unsigned)h[6] | ((unsigned)h[7] << 16);
  *(uint4*)&out[off] = pk;
}

// -------- recompute fp32 DCT, mask, IDCT -> clean [b][ch][gh][r][gw*16+cpos] --------
__global__ __launch_bounds__(256)
void mask_idct(const float* __restrict__ x, const unsigned short* __restrict__ masks,
               unsigned short* __restrict__ clean) {
  __shared__ float trp[TRS_SZ];
  const int tid = threadIdx.x;
  const int b   = blockIdx.y;
  const int c0  = blockIdx.x * 16;
  const int t = tid >> 4, q = tid & 15;
  const int c = c0 + t;
  const bool valid = (c < C0R);
  const int ch = c % 3, gw = (c / 3) % GD, gh = c / (3 * GD);

  float p[16];
  {
    float4 v0{}, v1{}, v2{}, v3{};
    if (valid) {
      const float* xr = x + ((size_t)(b * 3 + ch) * INSZ + (gh * 4 + q)) * INSZ + gw * 4;
      v0 = *(const float4*)(xr);      v1 = *(const float4*)(xr + 4);
      v2 = *(const float4*)(xr + 8);  v3 = *(const float4*)(xr + 12);
    }
    p[0]=v0.x; p[1]=v0.y; p[2]=v0.z; p[3]=v0.w;
    p[4]=v1.x; p[5]=v1.y; p[6]=v1.z; p[7]=v1.w;
    p[8]=v2.x; p[9]=v2.y; p[10]=v2.z; p[11]=v2.w;
    p[12]=v3.x; p[13]=v3.y; p[14]=v3.z; p[15]=v3.w;
  }
  float r[16];
#pragma unroll
  for (int k = 0; k < 16; ++k) {
    float s = 0.f;
#pragma unroll
    for (int n = 0; n < 16; ++n) s += p[n] * Dfwd(k, n);
    r[k] = s;
  }
  {
    float* wr = &trp[t * TRS_T + q * TRS_R];
#pragma unroll
    for (int k = 0; k < 16; k += 4)
      *(float4*)(wr + k) = make_float4(r[k], r[k+1], r[k+2], r[k+3]);
  }
  __syncthreads();
  const int j = q;
  float rr[16];
#pragma unroll
  for (int i = 0; i < 16; ++i) rr[i] = trp[t * TRS_T + i * TRS_R + j];
  float cd[16];
  const unsigned short* mrow = masks + (size_t)c * NTOK + (size_t)b * 256 + j;
#pragma unroll
  for (int k = 0; k < 16; ++k) {
    float s = 0.f;
#pragma unroll
    for (int i = 0; i < 16; ++i) s += rr[i] * Dfwd(k, i);
    const float mv = valid ? bf2f(mrow[k * 16]) : 0.f;
    cd[k] = s * mv;
  }
  float t3[16];
#pragma unroll
  for (int m = 0; m < 16; ++m) {
    float s = 0.f;
#pragma unroll
    for (int k = 0; k < 16; ++k) s += cd[k] * Dinv(m, k);
    t3[m] = s;
  }
  __syncthreads();
  {
    float* wr = &trp[t * TRS_T + j * TRS_R];
#pragma unroll
    for (int m = 0; m < 16; m += 4)
      *(float4*)(wr + m) = make_float4(t3[m], t3[m+1], t3[m+2], t3[m+3]);
  }
  __syncthreads();
  float tr[16];
#pragma unroll
  for (int l = 0; l < 16; ++l) tr[l] = trp[t * TRS_T + l * TRS_R + q];
  if (valid) {
    unsigned pk[8];
#pragma unroll
    for (int n2 = 0; n2 < 8; ++n2) {
      float s0 = 0.f, s1 = 0.f;
#pragma unroll
      for (int l = 0; l < 16; ++l) {
        s0 += tr[l] * Dinv(2 * n2, l);
        s1 += tr[l] * Dinv(2 * n2 + 1, l);
      }
      pk[n2] = (unsigned)f2bf(s0) | ((unsigned)f2bf(s1) << 16);
    }
    unsigned short* dst = clean +
        ((((size_t)(b * 3 + ch) * GD + gh) * 16 + q) * CROW) + gw * 16;
    uint4* d4 = (uint4*)dst;
    d4[0] = make_uint4(pk[0], pk[1], pk[2], pk[3]);
    d4[1] = make_uint4(pk[4], pk[5], pk[6], pk[7]);
  }
}

// -------- overlap-add gather (coalesced rows) + count normalization --------
__global__ void overlap_add(const unsigned short* __restrict__ clean, float* __restrict__ out) {
  const int px = blockIdx.x * 256 + threadIdx.x;
  if (px >= 8 * 3 * 224 * 224) return;
  const int j = px % 224;
  const int i = (px / 224) % 224;
  const int bc = px / (224 * 224);
  const int ilo = i - 15;
  const int ghlo = ilo > 0 ? (ilo + 3) >> 2 : 0;
  const int ghhi = (i >> 2) < 52 ? (i >> 2) : 52;
  const int jlo = j - 15;
  const int gwlo = jlo > 0 ? (jlo + 3) >> 2 : 0;
  const int gwhi = (j >> 2) < 52 ? (j >> 2) : 52;
  float sum = 0.f;
  for (int gh = ghlo; gh <= ghhi; ++gh) {
    const int r = i - gh * 4;
    const unsigned short* row = clean + (((size_t)bc * GD + gh) * 16 + r) * CROW;
    for (int gw = gwlo; gw <= gwhi; ++gw)
      sum += bf2f(row[j + 12 * gw]);
  }
  const int cnt = (ghhi - ghlo + 1) * (gwhi - gwlo + 1);
  out[px] = sum / (float)cnt;
}

extern "C" void kernel_launch(void* const* d_in, const int* in_sizes, int n_in,
                              void* d_out, int out_size, void* d_ws, size_t ws_size,
                              hipStream_t stream) {
  const float* x  = (const float*)d_in[0];
  const float* w1 = (const float*)d_in[1];
  const float* b1 = (const float*)d_in[2];
  const float* w2 = (const float*)d_in[3];
  const float* b2 = (const float*)d_in[4];
  const float* w3 = (const float*)d_in[5];
  const float* b3 = (const float*)d_in[6];
  const float* w4 = (const float*)d_in[7];
  const float* b4 = (const float*)d_in[8];
  float* out = (float*)d_out;
  char* ws = (char*)d_ws;

  // ---- workspace regions (peak 130.15 MB) ----
  const size_t OFF_A = 0;
  const size_t OFF_B = 38928384;
  const size_t OFF_C = 73531392;

  unsigned short* wb1   = (unsigned short*)(ws + OFF_A);
  unsigned short* wb4   = (unsigned short*)(ws + OFF_A);
  unsigned short* clean = (unsigned short*)(ws + OFF_A);

  unsigned short* H0v = (unsigned short*)(ws + OFF_B);
  unsigned short* Y1  = (unsigned short*)(ws + OFF_B);
  unsigned short* wb2 = (unsigned short*)(ws + OFF_B + 9437184);
  unsigned short* wb3 = (unsigned short*)(ws + OFF_B + 12386304);
  unsigned short* Y2  = (unsigned short*)(ws + OFF_B + 15335424);
  unsigned short* msk = (unsigned short*)(ws + OFF_B);

  float* pt1 = (float*)(ws + OFF_C);
  float* pt2 = (float*)(ws + OFF_C);
  float* pt3 = (float*)(ws + OFF_C);
  float* pt4 = (float*)(ws + OFF_C);
  unsigned short* Y3 = (unsigned short*)(ws + OFF_C + 37748736);

  // 1. w1 conversion + DCT
  cvt_pad8_w1<<<dim3(CV1_TOT / 256), 256, 0, stream>>>(w1, wb1);
  dct_h0<<<dim3(C0P / 64, 8), 256, 0, stream>>>(x, H0v);

  // 2. GEMM1: 256^2 split-K x3, grid (by=8, bx=9, z=3) -> B-panel pinned per XCD
  gemm256<0, 1, 1><<<dim3(NTOK / 256, C1P / 256, 3), 512, 0, stream>>>(
      wb1, H0v, nullptr, pt1, C1P, C0P, 2816);

  // 3. fused: GEMM1 reduce -> Y1 || w2/w3/w4 conversion
  mid1<<<dim3(M1_RB + CV8_T / 256), 256, 0, stream>>>(
      pt1, b1, Y1, w2, w3, w4, wb2, wb3, wb4);

  // 4. GEMM2 split-K x4 (chunk 544) -> Y2
  gemm_splitk<<<dim3(C2P / 128, NTOK / 128, 4), 256, 0, stream>>>(wb2, Y1, pt2, C2P, C1P, 544);
  reduce_act<<<dim3(NTOK * C2P / 8 / 256), 256, 0, stream>>>(pt2, b2, Y2, C2P, C2R, 4);

  // 5. GEMM3 split-K x2 (chunk 288) -> Y3
  gemm_splitk<<<dim3(C1P / 128, NTOK / 128, 2), 256, 0, stream>>>(wb3, Y2, pt3, C1P, C2P, 288);
  reduce_act<<<dim3(NTOK * C1P / 8 / 256), 256, 0, stream>>>(pt3, b3, Y3, C1P, C1R, 2);

  // 6. GEMM4: 256^2 main, grid (by=8, bx=32) -> B pinned per XCD; + tail + sigmoid
  gemm256<2, 0, 0><<<dim3(NTOK / 256, 32), 512, 0, stream>>>(
      wb4, Y3, b4, msk, NTOK, C1P, K1EFF);
  gemm_splitk_mn<<<dim3(2, NTOK / 128, 3), 256, 0, stream>>>(
      wb4 + (size_t)8192 * C1P, Y3, pt4, C1P, 704);
  reduce_sig<<<dim3(256 * NTOK / 8 / 256), 256, 0, stream>>>(pt4, b4, msk, 8192, 256, 3);

  // 7. mask*DCT -> IDCT -> clean (coalesced layout)
  mask_idct<<<dim3((C0R + 15) / 16, 8), 256, 0, stream>>>(x, msk, clean);

  // 8. overlap-add + normalize
  overlap_add<<<dim3((8 * 3 * 224 * 224 + 255) / 256), 256, 0, stream>>>(clean, out);
}

// Round 16
// 382.020 us; speedup vs baseline: 1.0078x; 1.0078x over previous
//
#include <hip/hip_runtime.h>
#include <stdint.h>

constexpr int INSZ = 224;
constexpr int GD   = 53;
constexpr int C0R = 8427, C1R = 2106, C2R = 526;
constexpr int C0P = 8448, C1P = 2304, C2P = 640;   // padded strides
constexpr int NTOK = 2048;
constexpr int CROW = GD * 16;  // 848
constexpr int K1EFF = 2112;    // GEMM4 main: 66 kt

typedef __attribute__((ext_vector_type(4))) float f32x4;
typedef __attribute__((ext_vector_type(8))) short bf16x8;

constexpr float CT[64] = {
  1.00000000f,  0.99518473f,  0.98078528f,  0.95694034f,
  0.92387953f,  0.88192126f,  0.83146961f,  0.77301045f,
  0.70710678f,  0.63439328f,  0.55557023f,  0.47139674f,
  0.38268343f,  0.29028468f,  0.19509032f,  0.09801714f,
  0.00000000f, -0.09801714f, -0.19509032f, -0.29028468f,
 -0.38268343f, -0.47139674f, -0.55557023f, -0.63439328f,
 -0.70710678f, -0.77301045f, -0.83146961f, -0.88192126f,
 -0.92387953f, -0.95694034f, -0.98078528f, -0.99518473f,
 -1.00000000f, -0.99518473f, -0.98078528f, -0.95694034f,
 -0.92387953f, -0.88192126f, -0.83146961f, -0.77301045f,
 -0.70710678f, -0.63439328f, -0.55557023f, -0.47139674f,
 -0.38268343f, -0.29028468f, -0.19509032f, -0.09801714f,
 -0.00000000f,  0.09801714f,  0.19509032f,  0.29028468f,
  0.38268343f,  0.47139674f,  0.55557023f,  0.63439328f,
  0.70710678f,  0.77301045f,  0.83146961f,  0.88192126f,
  0.92387953f,  0.95694034f,  0.98078528f,  0.99518473f
};
constexpr float Dfwd(int k, int n) { return 2.0f * CT[((2 * n + 1) * k) & 63]; }
constexpr float Dinv(int n, int k) { return CT[((2 * n + 1) * k) & 63] * (k == 0 ? 0.03125f : 0.0625f); }

constexpr int TRS_R = 20, TRS_T = 336;
constexpr int TRS_SZ = 15 * TRS_T + 15 * TRS_R + 16;
constexpr int HST_S = 68;   // hst row stride (ushorts): 136B breaks the 128B bank period

__device__ __forceinline__ unsigned short f2bf(float f) {
  union { float f; unsigned u; } v; v.f = f;
  return (unsigned short)((v.u + 0x7FFFu + ((v.u >> 16) & 1u)) >> 16);
}
__device__ __forceinline__ float bf2f(unsigned short b) {
  union { unsigned u; float f; } v; v.u = ((unsigned)b) << 16;
  return v.f;
}

__device__ __forceinline__ void gload_lds16(const void* g, void* l) {
  __builtin_amdgcn_global_load_lds(
      (__attribute__((address_space(1))) unsigned int*)(uintptr_t)g,
      (__attribute__((address_space(3))) unsigned int*)(unsigned int)(uintptr_t)l,
      16, 0, 0);
}

// XCD swizzle + L2 supertiling (4-wide bx stripes, by inner). requires (gx*gy)%8==0
__device__ __forceinline__ void xcd_tile(int& bx, int& by) {
  const int gx = gridDim.x, gy = gridDim.y;
  const int nwg = gx * gy;
  const int bid = blockIdx.y * gx + blockIdx.x;
  const int cpx = nwg >> 3;
  const int l = (bid & 7) * cpx + (bid >> 3);
  const int stripe = gy << 2;
  const int bxg = l / stripe;
  const int r = l - bxg * stripe;
  const int rem = gx - (bxg << 2);
  const int w = rem < 4 ? rem : 4;
  by = r / w;
  bx = (bxg << 2) + (r - by * w);
}

// -------- w1 fp32 -> bf16 padded, 8 elems/thread, uint4 store (no LDS) --------
constexpr int CV1_GPR = C0P / 8;
constexpr int CV1_TOT = C1P * CV1_GPR;
__global__ __launch_bounds__(256)
void cvt_pad8_w1(const float* __restrict__ src, unsigned short* __restrict__ dst) {
  const int i = blockIdx.x * 256 + threadIdx.x;
  if (i >= CV1_TOT) return;
  const int m = i / CV1_GPR;
  const int k0 = (i - m * CV1_GPR) * 8;
  const float* sr = src + (size_t)m * C0R + k0;
  const bool mok = (m < C1R);
  unsigned short h[8];
#pragma unroll
  for (int e = 0; e < 8; ++e)
    h[e] = f2bf((mok && k0 + e < C0R) ? sr[e] : 0.f);
  uint4 pk;
  pk.x = (unsigned)h[0] | ((unsigned)h[1] << 16);
  pk.y = (unsigned)h[2] | ((unsigned)h[3] << 16);
  pk.z = (unsigned)h[4] | ((unsigned)h[5] << 16);
  pk.w = (unsigned)h[6] | ((unsigned)h[7] << 16);
  *(uint4*)&dst[(size_t)m * C0P + k0] = pk;
}

// -------- DCT: x -> H0 bf16 [n=2048][c=8448]; hst stride 68 kills bank conflicts --------
__global__ __launch_bounds__(256)
void dct_h0(const float* __restrict__ x, unsigned short* __restrict__ H0) {
  __shared__ float trp[TRS_SZ];
  __shared__ unsigned short hst[256 * HST_S];
  const int tid = threadIdx.x;
  const int b   = blockIdx.y;
  const int c0  = blockIdx.x * 64;
  const int t = tid >> 4, q = tid & 15;

  for (int g = 0; g < 4; ++g) {
    const int c = c0 + g * 16 + t;
    float p[16];
    {
      float4 v0{}, v1{}, v2{}, v3{};
      if (c < C0R) {
        const int ch = c % 3, gw = (c / 3) % GD, gh = c / (3 * GD);
        const float* xr = x + ((size_t)(b * 3 + ch) * INSZ + (gh * 4 + q)) * INSZ + gw * 4;
        v0 = *(const float4*)(xr);      v1 = *(const float4*)(xr + 4);
        v2 = *(const float4*)(xr + 8);  v3 = *(const float4*)(xr + 12);
      }
      p[0]=v0.x; p[1]=v0.y; p[2]=v0.z; p[3]=v0.w;
      p[4]=v1.x; p[5]=v1.y; p[6]=v1.z; p[7]=v1.w;
      p[8]=v2.x; p[9]=v2.y; p[10]=v2.z; p[11]=v2.w;
      p[12]=v3.x; p[13]=v3.y; p[14]=v3.z; p[15]=v3.w;
    }
    float r[16];
#pragma unroll
    for (int k = 0; k < 16; ++k) {
      float s = 0.f;
#pragma unroll
      for (int n = 0; n < 16; ++n) s += p[n] * Dfwd(k, n);
      r[k] = s;
    }
    float* wr = &trp[t * TRS_T + q * TRS_R];
#pragma unroll
    for (int k = 0; k < 16; k += 4)
      *(float4*)(wr + k) = make_float4(r[k], r[k+1], r[k+2], r[k+3]);
    __syncthreads();
    const int j = q;
    float rr[16];
#pragma unroll
    for (int i = 0; i < 16; ++i) rr[i] = trp[t * TRS_T + i * TRS_R + j];
#pragma unroll
    for (int k = 0; k < 16; ++k) {
      float s = 0.f;
#pragma unroll
      for (int i = 0; i < 16; ++i) s += rr[i] * Dfwd(k, i);
      hst[(k * 16 + j) * HST_S + g * 16 + t] = f2bf(s * (1.f / 256.f));
    }
    __syncthreads();
  }
  const size_t base = ((size_t)b * 256) * C0P + c0;
#pragma unroll
  for (int i = 0; i < 8; ++i) {
    const int s = i * 256 + tid;
    const int kl = s >> 3, c16 = s & 7;
    *(uint4*)&H0[base + (size_t)kl * C0P + c16 * 8] = *(const uint4*)&hst[kl * HST_S + c16 * 8];
  }
}

// ======== fused stage 2: reduce_act(GEMM1) || cvt_pad8_all (no LDS) ========
constexpr int M1_RB = NTOK * C1P / 8 / 256;
constexpr int CV8_1 = C2P * C1P / 8;
constexpr int CV8_2 = CV8_1 + C1P * C2P / 8;
constexpr int CV8_T = CV8_2 + C0P * C1P / 8;
__global__ __launch_bounds__(256)
void mid1(const float* __restrict__ part, const float* __restrict__ b1,
          unsigned short* __restrict__ Y1,
          const float* __restrict__ w2, const float* __restrict__ w3,
          const float* __restrict__ w4, unsigned short* __restrict__ d2,
          unsigned short* __restrict__ d3, unsigned short* __restrict__ d4) {
  const int tid = threadIdx.x;
  if ((int)blockIdx.x < M1_RB) {
    const int i8 = blockIdx.x * 256 + tid;
    const size_t off = (size_t)i8 * 8;
    const int m0 = (int)(off % C1P);
    float s[8] = {0.f, 0.f, 0.f, 0.f, 0.f, 0.f, 0.f, 0.f};
    for (int z = 0; z < 3; ++z) {
      const float4 v0 = *(const float4*)(part + (size_t)z * NTOK * C1P + off);
      const float4 v1 = *(const float4*)(part + (size_t)z * NTOK * C1P + off + 4);
      s[0] += v0.x; s[1] += v0.y; s[2] += v0.z; s[3] += v0.w;
      s[4] += v1.x; s[5] += v1.y; s[6] += v1.z; s[7] += v1.w;
    }
    unsigned short h[8];
#pragma unroll
    for (int e = 0; e < 8; ++e) {
      const float b = (m0 + e < C1R) ? b1[m0 + e] : 0.f;
      h[e] = f2bf(fmaxf(s[e] + b, 0.f));
    }
    uint4 pk;
    pk.x = (unsigned)h[0] | ((unsigned)h[1] << 16);
    pk.y = (unsigned)h[2] | ((unsigned)h[3] << 16);
    pk.z = (unsigned)h[4] | ((unsigned)h[5] << 16);
    pk.w = (unsigned)h[6] | ((unsigned)h[7] << 16);
    *(uint4*)&Y1[off] = pk;
    return;
  }
  const int i = (blockIdx.x - M1_RB) * 256 + tid;
  const float* src; unsigned short* dst;
  int m, k0, Kreal, Mreal, Kp;
  if (i < CV8_1) {
    const int gpr = C1P / 8;
    m = i / gpr; k0 = (i - m * gpr) * 8;
    src = w2; dst = d2; Mreal = C2R; Kreal = C1R; Kp = C1P;
  } else if (i < CV8_2) {
    const int j = i - CV8_1;
    const int gpr = C2P / 8;
    m = j / gpr; k0 = (j - m * gpr) * 8;
    src = w3; dst = d3; Mreal = C1R; Kreal = C2R; Kp = C2P;
  } else {
    const int j = i - CV8_2;
    const int gpr = C1P / 8;
    m = j / gpr; k0 = (j - m * gpr) * 8;
    src = w4; dst = d4; Mreal = C0R; Kreal = C1R; Kp = C1P;
  }
  const float* sr = src + (size_t)m * Kreal + k0;
  const bool mok = (m < Mreal);
  unsigned short h[8];
#pragma unroll
  for (int e = 0; e < 8; ++e)
    h[e] = f2bf((mok && k0 + e < Kreal) ? sr[e] : 0.f);
  uint4 pk;
  pk.x = (unsigned)h[0] | ((unsigned)h[1] << 16);
  pk.y = (unsigned)h[2] | ((unsigned)h[3] << 16);
  pk.z = (unsigned)h[4] | ((unsigned)h[5] << 16);
  pk.w = (unsigned)h[6] | ((unsigned)h[7] << 16);
  *(uint4*)&dst[(size_t)m * Kp + k0] = pk;
}

// ======== 256x256 deep-pipelined GEMM (frozen schedule, xcd_tile supertile) ========
template<int ACT, int OUT_NM, int SPLITK>
__global__ __launch_bounds__(512, 2)
void gemm256(const unsigned short* __restrict__ W, const unsigned short* __restrict__ Ht,
             const float* __restrict__ bias, void* __restrict__ outp,
             int ldo, int Kp, int chunkK) {
  __shared__ unsigned short As[4][8192];
  __shared__ unsigned short Bs[4][8192];
  int bx, by; xcd_tile(bx, by);
  const int m0 = bx * 256, n0 = by * 256;
  const int tid = threadIdx.x;
  const int w = tid >> 6, lane = tid & 63;
  const int wr = w >> 2, wc = w & 3;
  const int lhi = lane >> 4, llo = lane & 15;
  const int kbase = SPLITK ? blockIdx.z * chunkK : 0;
  const int nkt = chunkK >> 5;

  const int srow = tid >> 2;
  const int slgc = ((tid & 3) ^ ((srow >> 1) & 3)) * 8;

  f32x4 acc[8][4];
#pragma unroll
  for (int i = 0; i < 8; ++i)
#pragma unroll
    for (int j = 0; j < 4; ++j) acc[i][j] = f32x4{0.f, 0.f, 0.f, 0.f};

  auto STAGE_A = [&](int kt, int buf) {
    const int kb = kbase + kt * 32 + slgc;
    gload_lds16(W + (size_t)(m0 + srow) * Kp + kb,       &As[buf][w * 512]);
    gload_lds16(W + (size_t)(m0 + 128 + srow) * Kp + kb, &As[buf][4096 + w * 512]);
  };
  auto STAGE_B = [&](int kt, int buf) {
    const int kb = kbase + kt * 32 + slgc;
    gload_lds16(Ht + (size_t)(n0 + srow) * Kp + kb,       &Bs[buf][w * 512]);
    gload_lds16(Ht + (size_t)(n0 + 128 + srow) * Kp + kb, &Bs[buf][4096 + w * 512]);
  };

  STAGE_A(0, 0); STAGE_B(0, 0);
  if (nkt > 1) { STAGE_A(1, 1); STAGE_B(1, 1); }
  if (nkt > 2) { STAGE_A(2, 2); STAGE_B(2, 2); }

  for (int kt = 0; kt < nkt; ++kt) {
    const int buf  = kt & 3;
    const int sbuf = (kt + 3) & 3;
    if (kt + 3 <= nkt)      asm volatile("s_waitcnt vmcnt(8)" ::: "memory");
    else if (kt + 2 == nkt) asm volatile("s_waitcnt vmcnt(4)" ::: "memory");
    else                    asm volatile("s_waitcnt vmcnt(0)" ::: "memory");
    __builtin_amdgcn_s_barrier();
    __builtin_amdgcn_sched_barrier(0);

    bf16x8 af[4], bfr[4];
    // phase A: m-half 0 + all B frags
#pragma unroll
    for (int mi = 0; mi < 4; ++mi) {
      const int row = wr * 128 + mi * 16 + llo;
      af[mi] = *(const bf16x8*)(&As[buf][row * 32 + ((lhi ^ ((row >> 1) & 3)) << 3)]);
    }
#pragma unroll
    for (int ni = 0; ni < 4; ++ni) {
      const int row = wc * 64 + ni * 16 + llo;
      bfr[ni] = *(const bf16x8*)(&Bs[buf][row * 32 + ((lhi ^ ((row >> 1) & 3)) << 3)]);
    }
    if (kt + 3 < nkt) STAGE_A(kt + 3, sbuf);
    __builtin_amdgcn_s_setprio(1);
#pragma unroll
    for (int mi = 0; mi < 4; ++mi)
#pragma unroll
      for (int ni = 0; ni < 4; ++ni)
        acc[mi][ni] = OUT_NM
          ? __builtin_amdgcn_mfma_f32_16x16x32_bf16(bfr[ni], af[mi], acc[mi][ni], 0, 0, 0)
          : __builtin_amdgcn_mfma_f32_16x16x32_bf16(af[mi], bfr[ni], acc[mi][ni], 0, 0, 0);
    __builtin_amdgcn_s_setprio(0);
    // phase B: m-half 1, reuse bfr
#pragma unroll
    for (int mi = 0; mi < 4; ++mi) {
      const int row = wr * 128 + 64 + mi * 16 + llo;
      af[mi] = *(const bf16x8*)(&As[buf][row * 32 + ((lhi ^ ((row >> 1) & 3)) << 3)]);
    }
    if (kt + 3 < nkt) STAGE_B(kt + 3, sbuf);
    __builtin_amdgcn_s_setprio(1);
#pragma unroll
    for (int mi = 0; mi < 4; ++mi)
#pragma unroll
      for (int ni = 0; ni < 4; ++ni)
        acc[4 + mi][ni] = OUT_NM
          ? __builtin_amdgcn_mfma_f32_16x16x32_bf16(bfr[ni], af[mi], acc[4 + mi][ni], 0, 0, 0)
          : __builtin_amdgcn_mfma_f32_16x16x32_bf16(af[mi], bfr[ni], acc[4 + mi][ni], 0, 0, 0);
    __builtin_amdgcn_s_setprio(0);
  }

  if (SPLITK) {
    float* pz = (float*)outp + (size_t)blockIdx.z * ((size_t)NTOK * ldo);
#pragma unroll
    for (int mh = 0; mh < 2; ++mh)
#pragma unroll
      for (int mi = 0; mi < 4; ++mi) {
        const int mg = m0 + wr * 128 + mh * 64 + mi * 16 + llo;
#pragma unroll
        for (int ni = 0; ni < 4; ++ni) {
          const int ng = n0 + wc * 64 + ni * 16 + lhi * 4;
#pragma unroll
          for (int r = 0; r < 4; ++r)
            pz[(size_t)(ng + r) * ldo + mg] = acc[mh * 4 + mi][ni][r];
        }
      }
  } else {
    unsigned short* out = (unsigned short*)outp;
#pragma unroll
    for (int mh = 0; mh < 2; ++mh)
#pragma unroll
      for (int mi = 0; mi < 4; ++mi) {
        const int mgb = m0 + wr * 128 + mh * 64 + mi * 16 + lhi * 4;
#pragma unroll
        for (int ni = 0; ni < 4; ++ni) {
          const int ng = n0 + wc * 64 + ni * 16 + llo;
#pragma unroll
          for (int r = 0; r < 4; ++r) {
            const int mg = mgb + r;
            float v = acc[mh * 4 + mi][ni][r] + bias[mg];
            if (ACT == 1) v = fmaxf(v, 0.f);
            else if (ACT == 2) v = 1.f / (1.f + expf(-v));
            out[(size_t)mg * ldo + ng] = f2bf(v);
          }
        }
      }
  }
}

// ======== 128x128 core (GEMM2/3 + GEMM4 tail splitk) ========
template<int OUT_NM>
__device__ __forceinline__ void gemm_core(
    const unsigned short* __restrict__ W, const unsigned short* __restrict__ Ht,
    unsigned short (*As)[128 * 32], unsigned short (*Bs)[128 * 32],
    int m0, int n0, int Kp, int kbase, int nkt, int w, int lane, f32x4 acc[4][4]) {
  const int wr = w >> 1, wc = w & 1;
  const int lhi = lane >> 4, llo = lane & 15;

  const int chunk0 = w * 64 + lane;
  const int row0 = chunk0 >> 2, kc0 = chunk0 & 3;
  const int kcg0 = kc0 ^ ((row0 >> 1) & 3);
  const int chunk1 = 256 + w * 64 + lane;
  const int row1 = chunk1 >> 2, kc1 = chunk1 & 3;
  const int kcg1 = kc1 ^ ((row1 >> 1) & 3);

  auto STAGE = [&](int kt, int sel) {
    const int kb = kbase + kt * 32;
    gload_lds16(W  + (size_t)(m0 + row0) * Kp + kb + kcg0 * 8, &As[sel][(w * 64) * 8]);
    gload_lds16(Ht + (size_t)(n0 + row0) * Kp + kb + kcg0 * 8, &Bs[sel][(w * 64) * 8]);
    gload_lds16(W  + (size_t)(m0 + row1) * Kp + kb + kcg1 * 8, &As[sel][(256 + w * 64) * 8]);
    gload_lds16(Ht + (size_t)(n0 + row1) * Kp + kb + kcg1 * 8, &Bs[sel][(256 + w * 64) * 8]);
  };

  STAGE(0, 0);
  if (nkt > 1) STAGE(1, 1);

  int cur = 0, nxt = 1, nx2 = 2;
  for (int kt = 0; kt < nkt; ++kt) {
    if (kt + 1 < nkt) {
      asm volatile("s_waitcnt vmcnt(4)" ::: "memory");
      __builtin_amdgcn_s_barrier();
      __builtin_amdgcn_sched_barrier(0);
      if (kt + 2 < nkt) STAGE(kt + 2, nx2);
    } else {
      asm volatile("s_waitcnt vmcnt(0)" ::: "memory");
      __builtin_amdgcn_s_barrier();
      __builtin_amdgcn_sched_barrier(0);
    }
    bf16x8 af[4], bfr[4];
#pragma unroll
    for (int mi = 0; mi < 4; ++mi) {
      const int row = wr * 64 + mi * 16 + llo;
      af[mi] = *(const bf16x8*)(&As[cur][row * 32 + (lhi ^ ((row >> 1) & 3)) * 8]);
    }
#pragma unroll
    for (int ni = 0; ni < 4; ++ni) {
      const int row = wc * 64 + ni * 16 + llo;
      bfr[ni] = *(const bf16x8*)(&Bs[cur][row * 32 + (lhi ^ ((row >> 1) & 3)) * 8]);
    }
#pragma unroll
    for (int mi = 0; mi < 4; ++mi)
#pragma unroll
      for (int ni = 0; ni < 4; ++ni) {
        if (OUT_NM)
          acc[mi][ni] = __builtin_amdgcn_mfma_f32_16x16x32_bf16(bfr[ni], af[mi], acc[mi][ni], 0, 0, 0);
        else
          acc[mi][ni] = __builtin_amdgcn_mfma_f32_16x16x32_bf16(af[mi], bfr[ni], acc[mi][ni], 0, 0, 0);
      }
    const int tmp = cur; cur = nxt; nxt = nx2; nx2 = tmp;
  }
}

// -------- 128^2 split-K, n-major partials [z][n][m] (GEMM2/3) --------
__global__ __launch_bounds__(256)
void gemm_splitk(const unsigned short* __restrict__ W, const unsigned short* __restrict__ Ht,
                 float* __restrict__ part, int ldo /*Mp*/, int Kp, int chunkK) {
  __shared__ unsigned short As[3][128 * 32];
  __shared__ unsigned short Bs[3][128 * 32];
  int bx, by; xcd_tile(bx, by);
  const int z = blockIdx.z;
  const int tid = threadIdx.x;
  const int w = tid >> 6, lane = tid & 63;
  const int m0 = bx * 128, n0 = by * 128;
  const int wr = w >> 1, wc = w & 1;
  const int lhi = lane >> 4, llo = lane & 15;

  f32x4 acc[4][4];
#pragma unroll
  for (int i = 0; i < 4; ++i)
#pragma unroll
    for (int j = 0; j < 4; ++j) acc[i][j] = f32x4{0.f, 0.f, 0.f, 0.f};

  gemm_core<1>(W, Ht, As, Bs, m0, n0, Kp, z * chunkK, chunkK >> 5, w, lane, acc);

  float* pz = part + (size_t)z * NTOK * ldo;
#pragma unroll
  for (int mi = 0; mi < 4; ++mi) {
    const int mg = m0 + wr * 64 + mi * 16 + llo;
#pragma unroll
    for (int ni = 0; ni < 4; ++ni) {
      const int ng = n0 + wc * 64 + ni * 16 + lhi * 4;
#pragma unroll
      for (int r = 0; r < 4; ++r)
        pz[(size_t)(ng + r) * ldo + mg] = acc[mi][ni][r];
    }
  }
}

// -------- 128^2 split-K, m-major partials [z][m_local][n] (GEMM4 tail) --------
__global__ __launch_bounds__(256)
void gemm_splitk_mn(const unsigned short* __restrict__ W, const unsigned short* __restrict__ Ht,
                    float* __restrict__ part, int Kp, int chunkK) {
  __shared__ unsigned short As[3][128 * 32];
  __shared__ unsigned short Bs[3][128 * 32];
  int bx, by; xcd_tile(bx, by);
  const int z = blockIdx.z;
  const int tid = threadIdx.x;
  const int w = tid >> 6, lane = tid & 63;
  const int m0 = bx * 128, n0 = by * 128;
  const int wr = w >> 1, wc = w & 1;
  const int lhi = lane >> 4, llo = lane & 15;
  const int Mloc = gridDim.x * 128;

  f32x4 acc[4][4];
#pragma unroll
  for (int i = 0; i < 4; ++i)
#pragma unroll
    for (int j = 0; j < 4; ++j) acc[i][j] = f32x4{0.f, 0.f, 0.f, 0.f};

  gemm_core<0>(W, Ht, As, Bs, m0, n0, Kp, z * chunkK, chunkK >> 5, w, lane, acc);

  float* pz = part + (size_t)z * Mloc * NTOK;
#pragma unroll
  for (int mi = 0; mi < 4; ++mi) {
    const int mlb = m0 + wr * 64 + mi * 16 + lhi * 4;
#pragma unroll
    for (int ni = 0; ni < 4; ++ni) {
      const int ng = n0 + wc * 64 + ni * 16 + llo;
#pragma unroll
      for (int r = 0; r < 4; ++r)
        pz[(size_t)(mlb + r) * NTOK + ng] = acc[mi][ni][r];
    }
  }
}

// -------- tail reduce + bias + sigmoid --------
__global__ __launch_bounds__(256)
void reduce_sig(const float* __restrict__ part, const float* __restrict__ bias,
                unsigned short* __restrict__ msk, int mbase, int Mloc, int nch) {
  const int i8 = blockIdx.x * 256 + threadIdx.x;
  const int total = Mloc * NTOK / 8;
  if (i8 >= total) return;
  const size_t off = (size_t)i8 * 8;
  const int ml = (int)(off >> 11);
  float s[8] = {0.f, 0.f, 0.f, 0.f, 0.f, 0.f, 0.f, 0.f};
  for (int z = 0; z < nch; ++z) {
    const float4 v0 = *(const float4*)(part + (size_t)z * Mloc * NTOK + off);
    const float4 v1 = *(const float4*)(part + (size_t)z * Mloc * NTOK + off + 4);
    s[0] += v0.x; s[1] += v0.y; s[2] += v0.z; s[3] += v0.w;
    s[4] += v1.x; s[5] += v1.y; s[6] += v1.z; s[7] += v1.w;
  }
  const int mg = mbase + ml;
  const float b = (mg < C0R) ? bias[mg] : 0.f;
  unsigned short h[8];
#pragma unroll
  for (int e = 0; e < 8; ++e)
    h[e] = f2bf(1.f / (1.f + expf(-(s[e] + b))));
  uint4 pk;
  pk.x = (unsigned)h[0] | ((unsigned)h[1] << 16);
  pk.y = (unsigned)h[2] | ((unsigned)h[3] << 16);
  pk.z = (unsigned)h[4] | ((unsigned)h[5] << 16);
  pk.w = (unsigned)h[6] | ((unsigned)h[7] << 16);
  *(uint4*)&msk[(size_t)mg * NTOK + (off & 2047)] = pk;
}

// -------- split-K reduce + bias + ReLU (GEMM2/3) --------
__global__ __launch_bounds__(256)
void reduce_act(const float* __restrict__ part, const float* __restrict__ bias,
                unsigned short* __restrict__ out, int Mp, int Mreal, int nch) {
  const int i8 = blockIdx.x * 256 + threadIdx.x;
  const int total = NTOK * Mp / 8;
  if (i8 >= total) return;
  const size_t off = (size_t)i8 * 8;
  const int m0 = (int)(off % Mp);
  float s[8] = {0.f, 0.f, 0.f, 0.f, 0.f, 0.f, 0.f, 0.f};
  for (int z = 0; z < nch; ++z) {
    const float4 v0 = *(const float4*)(part + (size_t)z * NTOK * Mp + off);
    const float4 v1 = *(const float4*)(part + (size_t)z * NTOK * Mp + off + 4);
    s[0] += v0.x; s[1] += v0.y; s[2] += v0.z; s[3] += v0.w;
    s[4] += v1.x; s[5] += v1.y; s[6] += v1.z; s[7] += v1.w;
  }
  unsigned short h[8];
#pragma unroll
  for (int e = 0; e < 8; ++e) {
    const float b = (m0 + e < Mreal) ? bias[m0 + e] : 0.f;
    h[e] = f2bf(fmaxf(s[e] + b, 0.f));
  }
  uint4 pk;
  pk.x = (unsigned)h[0] | ((unsigned)h[1] << 16);
  pk.y = (unsigned)h[2] | ((unsigned)h[3] << 16);
  pk.z = (unsigned)h[4] | ((unsigned)h[5] << 16);
  pk.w = (unsigned)h[6] | ((unsigned)h[7] << 16);
  *(uint4*)&out[off] = pk;
}

// -------- recompute fp32 DCT, mask, IDCT -> clean [b][ch][gh][r][gw*16+cpos] --------
__global__ __launch_bounds__(256)
void mask_idct(const float* __restrict__ x, const unsigned short* __restrict__ masks,
               unsigned short* __restrict__ clean) {
  __shared__ float trp[TRS_SZ];
  const int tid = threadIdx.x;
  const int b   = blockIdx.y;
  const int c0  = blockIdx.x * 16;
  const int t = tid >> 4, q = tid & 15;
  const int c = c0 + t;
  const bool valid = (c < C0R);
  const int ch = c % 3, gw = (c / 3) % GD, gh = c / (3 * GD);

  float p[16];
  {
    float4 v0{}, v1{}, v2{}, v3{};
    if (valid) {
      const float* xr = x + ((size_t)(b * 3 + ch) * INSZ + (gh * 4 + q)) * INSZ + gw * 4;
      v0 = *(const float4*)(xr);      v1 = *(const float4*)(xr + 4);
      v2 = *(const float4*)(xr + 8);  v3 = *(const float4*)(xr + 12);
    }
    p[0]=v0.x; p[1]=v0.y; p[2]=v0.z; p[3]=v0.w;
    p[4]=v1.x; p[5]=v1.y; p[6]=v1.z; p[7]=v1.w;
    p[8]=v2.x; p[9]=v2.y; p[10]=v2.z; p[11]=v2.w;
    p[12]=v3.x; p[13]=v3.y; p[14]=v3.z; p[15]=v3.w;
  }
  float r[16];
#pragma unroll
  for (int k = 0; k < 16; ++k) {
    float s = 0.f;
#pragma unroll
    for (int n = 0; n < 16; ++n) s += p[n] * Dfwd(k, n);
    r[k] = s;
  }
  {
    float* wr = &trp[t * TRS_T + q * TRS_R];
#pragma unroll
    for (int k = 0; k < 16; k += 4)
      *(float4*)(wr + k) = make_float4(r[k], r[k+1], r[k+2], r[k+3]);
  }
  __syncthreads();
  const int j = q;
  float rr[16];
#pragma unroll
  for (int i = 0; i < 16; ++i) rr[i] = trp[t * TRS_T + i * TRS_R + j];
  float cd[16];
  const unsigned short* mrow = masks + (size_t)c * NTOK + (size_t)b * 256 + j;
#pragma unroll
  for (int k = 0; k < 16; ++k) {
    float s = 0.f;
#pragma unroll
    for (int i = 0; i < 16; ++i) s += rr[i] * Dfwd(k, i);
    const float mv = valid ? bf2f(mrow[k * 16]) : 0.f;
    cd[k] = s * mv;
  }
  float t3[16];
#pragma unroll
  for (int m = 0; m < 16; ++m) {
    float s = 0.f;
#pragma unroll
    for (int k = 0; k < 16; ++k) s += cd[k] * Dinv(m, k);
    t3[m] = s;
  }
  __syncthreads();
  {
    float* wr = &trp[t * TRS_T + j * TRS_R];
#pragma unroll
    for (int m = 0; m < 16; m += 4)
      *(float4*)(wr + m) = make_float4(t3[m], t3[m+1], t3[m+2], t3[m+3]);
  }
  __syncthreads();
  float tr[16];
#pragma unroll
  for (int l = 0; l < 16; ++l) tr[l] = trp[t * TRS_T + l * TRS_R + q];
  if (valid) {
    unsigned pk[8];
#pragma unroll
    for (int n2 = 0; n2 < 8; ++n2) {
      float s0 = 0.f, s1 = 0.f;
#pragma unroll
      for (int l = 0; l < 16; ++l) {
        s0 += tr[l] * Dinv(2 * n2, l);
        s1 += tr[l] * Dinv(2 * n2 + 1, l);
      }
      pk[n2] = (unsigned)f2bf(s0) | ((unsigned)f2bf(s1) << 16);
    }
    unsigned short* dst = clean +
        ((((size_t)(b * 3 + ch) * GD + gh) * 16 + q) * CROW) + gw * 16;
    uint4* d4 = (uint4*)dst;
    d4[0] = make_uint4(pk[0], pk[1], pk[2], pk[3]);
    d4[1] = make_uint4(pk[4], pk[5], pk[6], pk[7]);
  }
}

// -------- overlap-add gather (coalesced rows) + count normalization --------
__global__ void overlap_add(const unsigned short* __restrict__ clean, float* __restrict__ out) {
  const int px = blockIdx.x * 256 + threadIdx.x;
  if (px >= 8 * 3 * 224 * 224) return;
  const int j = px % 224;
  const int i = (px / 224) % 224;
  const int bc = px / (224 * 224);
  const int ilo = i - 15;
  const int ghlo = ilo > 0 ? (ilo + 3) >> 2 : 0;
  const int ghhi = (i >> 2) < 52 ? (i >> 2) : 52;
  const int jlo = j - 15;
  const int gwlo = jlo > 0 ? (jlo + 3) >> 2 : 0;
  const int gwhi = (j >> 2) < 52 ? (j >> 2) : 52;
  float sum = 0.f;
  for (int gh = ghlo; gh <= ghhi; ++gh) {
    const int r = i - gh * 4;
    const unsigned short* row = clean + (((size_t)bc * GD + gh) * 16 + r) * CROW;
    for (int gw = gwlo; gw <= gwhi; ++gw)
      sum += bf2f(row[j + 12 * gw]);
  }
  const int cnt = (ghhi - ghlo + 1) * (gwhi - gwlo + 1);
  out[px] = sum / (float)cnt;
}

extern "C" void kernel_launch(void* const* d_in, const int* in_sizes, int n_in,
                              void* d_out, int out_size, void* d_ws, size_t ws_size,
                              hipStream_t stream) {
  const float* x  = (const float*)d_in[0];
  const float* w1 = (const float*)d_in[1];
  const float* b1 = (const float*)d_in[2];
  const float* w2 = (const float*)d_in[3];
  const float* b2 = (const float*)d_in[4];
  const float* w3 = (const float*)d_in[5];
  const float* b3 = (const float*)d_in[6];
  const float* w4 = (const float*)d_in[7];
  const float* b4 = (const float*)d_in[8];
  float* out = (float*)d_out;
  char* ws = (char*)d_ws;

  // ---- workspace regions (peak 130.15 MB) ----
  const size_t OFF_A = 0;
  const size_t OFF_B = 38928384;
  const size_t OFF_C = 73531392;

  unsigned short* wb1   = (unsigned short*)(ws + OFF_A);
  unsigned short* wb4   = (unsigned short*)(ws + OFF_A);
  unsigned short* clean = (unsigned short*)(ws + OFF_A);

  unsigned short* H0v = (unsigned short*)(ws + OFF_B);
  unsigned short* Y1  = (unsigned short*)(ws + OFF_B);
  unsigned short* wb2 = (unsigned short*)(ws + OFF_B + 9437184);
  unsigned short* wb3 = (unsigned short*)(ws + OFF_B + 12386304);
  unsigned short* Y2  = (unsigned short*)(ws + OFF_B + 15335424);
  unsigned short* msk = (unsigned short*)(ws + OFF_B);

  float* pt1 = (float*)(ws + OFF_C);
  float* pt2 = (float*)(ws + OFF_C);
  float* pt3 = (float*)(ws + OFF_C);
  float* pt4 = (float*)(ws + OFF_C);
  unsigned short* Y3 = (unsigned short*)(ws + OFF_C + 37748736);

  // 1. w1 conversion + DCT
  cvt_pad8_w1<<<dim3(CV1_TOT / 256), 256, 0, stream>>>(w1, wb1);
  dct_h0<<<dim3(C0P / 64, 8), 256, 0, stream>>>(x, H0v);

  // 2. GEMM1: 256^2 split-K x3 (216 blocks, supertiled)
  gemm256<0, 1, 1><<<dim3(C1P / 256, NTOK / 256, 3), 512, 0, stream>>>(
      wb1, H0v, nullptr, pt1, C1P, C0P, 2816);

  // 3. fused: GEMM1 reduce -> Y1 || w2/w3/w4 conversion
  mid1<<<dim3(M1_RB + CV8_T / 256), 256, 0, stream>>>(
      pt1, b1, Y1, w2, w3, w4, wb2, wb3, wb4);

  // 4. GEMM2 split-K x4 (chunk 544) -> Y2
  gemm_splitk<<<dim3(C2P / 128, NTOK / 128, 4), 256, 0, stream>>>(wb2, Y1, pt2, C2P, C1P, 544);
  reduce_act<<<dim3(NTOK * C2P / 8 / 256), 256, 0, stream>>>(pt2, b2, Y2, C2P, C2R, 4);

  // 5. GEMM3 split-K x2 (chunk 288) -> Y3
  gemm_splitk<<<dim3(C1P / 128, NTOK / 128, 2), 256, 0, stream>>>(wb3, Y2, pt3, C1P, C2P, 288);
  reduce_act<<<dim3(NTOK * C1P / 8 / 256), 256, 0, stream>>>(pt3, b3, Y3, C1P, C1R, 2);

  // 6. GEMM4: 256^2 main (supertiled) + split-K x3 tail + sigmoid
  gemm256<2, 0, 0><<<dim3(32, NTOK / 256), 512, 0, stream>>>(
      wb4, Y3, b4, msk, NTOK, C1P, K1EFF);
  gemm_splitk_mn<<<dim3(2, NTOK / 128, 3), 256, 0, stream>>>(
      wb4 + (size_t)8192 * C1P, Y3, pt4, C1P, 704);
  reduce_sig<<<dim3(256 * NTOK / 8 / 256), 256, 0, stream>>>(pt4, b4, msk, 8192, 256, 3);

  // 7. mask*DCT -> IDCT -> clean (coalesced layout)
  mask_idct<<<dim3((C0R + 15) / 16, 8), 256, 0, stream>>>(x, msk, clean);

  // 8. overlap-add + normalize
  overlap_add<<<dim3((8 * 3 * 224 * 224 + 255) / 256), 256, 0, stream>>>(clean, out);
}